// Round 3
// baseline (4285.432 us; speedup 1.0000x reference)
//
#include <hip/hip_runtime.h>
#include <hip/hip_bf16.h>

typedef __hip_bfloat16 bf16;

#define B_ 32
#define C_ 312
#define N_ 1024
#define H_ 8
#define D_ 128
#define SD_ 78
#define BC_ (B_ * C_)      // 9984
#define BH_ (B_ * H_)      // 256

__device__ __forceinline__ float bf2f(bf16 x) { return __bfloat162float(x); }
__device__ __forceinline__ bf16 f2bf(float x) { return __float2bfloat16(x); }
__device__ __forceinline__ float hswish(float x) {
    return x * fminf(fmaxf(x + 3.0f, 0.0f), 6.0f) * (1.0f / 6.0f);
}

struct alignas(8) bf16x4 { bf16 v[4]; };

// ---------------- LayerNorm (stats only; affine folded into GEMM A-load) ----
// x is fp32; xn is bf16 internal.
__global__ void ln_kernel(const float* __restrict__ x, bf16* __restrict__ xn) {
    int r = blockIdx.x;
    int t = threadIdx.x;
    const float* xr = x + (size_t)r * N_;
    float s = 0.f, sq = 0.f;
    for (int i = t; i < N_; i += 256) { float f = xr[i]; s += f; sq += f * f; }
    __shared__ float rs[256], rq[256];
    rs[t] = s; rq[t] = sq; __syncthreads();
    for (int o = 128; o > 0; o >>= 1) {
        if (t < o) { rs[t] += rs[t + o]; rq[t] += rq[t + o]; }
        __syncthreads();
    }
    float mu = rs[0] * (1.0f / N_);
    float var = rq[0] * (1.0f / N_) - mu * mu;
    float rstd = rsqrtf(var + 1e-5f);
    bf16* xo = xn + (size_t)r * N_;
    for (int i = t; i < N_; i += 256) xo[i] = f2bf((xr[i] - mu) * rstd);
}

// ---------------- Tiled GEMM: C[M,Nout] = A' * W^T (+bias) ------------------
#define BM 64
#define BN 64
#define BK 16
template <bool OUTF32>
__global__ void gemm_kernel(const bf16* __restrict__ A,
                            const float* __restrict__ G,   // K affine scale or null
                            const float* __restrict__ Bv,  // K affine bias or null
                            const float* __restrict__ W,   // Nout x K fp32
                            const float* __restrict__ bias,
                            void* __restrict__ Cout,
                            int M, int K, int Nout) {
    __shared__ float As[BK][BM + 1];
    __shared__ float Bs[BK][BN + 1];
    int t = threadIdx.x;
    int m0 = blockIdx.y * BM;
    int n0 = blockIdx.x * BN;
    int lm = t >> 2;            // 0..63
    int lk = (t & 3) * 4;       // 0,4,8,12
    int ty = t >> 4, tx = t & 15;
    float acc[4][4] = {};
    for (int k0 = 0; k0 < K; k0 += BK) {
        bf16x4 av = *reinterpret_cast<const bf16x4*>(A + (size_t)(m0 + lm) * K + k0 + lk);
        float4 wv = *reinterpret_cast<const float4*>(W + (size_t)(n0 + lm) * K + k0 + lk);
        if (G) {
#pragma unroll
            for (int j = 0; j < 4; j++)
                As[lk + j][lm] = bf2f(av.v[j]) * G[k0 + lk + j] + Bv[k0 + lk + j];
        } else {
#pragma unroll
            for (int j = 0; j < 4; j++) As[lk + j][lm] = bf2f(av.v[j]);
        }
        Bs[lk + 0][lm] = wv.x;
        Bs[lk + 1][lm] = wv.y;
        Bs[lk + 2][lm] = wv.z;
        Bs[lk + 3][lm] = wv.w;
        __syncthreads();
#pragma unroll
        for (int kk = 0; kk < BK; kk++) {
            float a[4], b[4];
#pragma unroll
            for (int i = 0; i < 4; i++) a[i] = As[kk][ty * 4 + i];
#pragma unroll
            for (int j = 0; j < 4; j++) b[j] = Bs[kk][tx * 4 + j];
#pragma unroll
            for (int i = 0; i < 4; i++)
#pragma unroll
                for (int j = 0; j < 4; j++) acc[i][j] += a[i] * b[j];
        }
        __syncthreads();
    }
#pragma unroll
    for (int i = 0; i < 4; i++) {
        int m = m0 + ty * 4 + i;
#pragma unroll
        for (int j = 0; j < 4; j++) {
            int n = n0 + tx * 4 + j;
            float v = acc[i][j];
            if (bias) v += bias[n];
            if (OUTF32) ((float*)Cout)[(size_t)m * Nout + n] = v;
            else        ((bf16*)Cout)[(size_t)m * Nout + n] = f2bf(v);
        }
    }
}

// ---------------- aggregator pieces -----------------------------------------
// writeback target: th[b, head, c_full, dd] = th[((b*8 + n>>7)*312 + c_full)*128 + (n&127)]

__global__ void seg0_kernel(const bf16* __restrict__ t, bf16* __restrict__ th,
                            const float* __restrict__ g, const float* __restrict__ b,
                            const float* __restrict__ m, const float* __restrict__ v) {
    int bc = blockIdx.x;
    int bi = bc / SD_, c = bc % SD_;
    float inv = g[c] * rsqrtf(v[c] + 1e-5f);
    float mm = m[c], bb = b[c];
    const bf16* tp = t + ((size_t)bi * C_ + c) * N_;
    bf16* base = th + (size_t)bi * H_ * C_ * D_;
    for (int n = threadIdx.x; n < N_; n += 256) {
        float y = hswish((bf2f(tp[n]) - mm) * inv + bb);
        base[((n >> 7) * C_ + c) * D_ + (n & 127)] = f2bf(y);
    }
}

template <int KS>
__global__ void dw_kernel(const bf16* __restrict__ t, int cOff,
                          const float* __restrict__ dw, float* __restrict__ outp) {
    int bc = blockIdx.x;
    int bi = bc / SD_, c = bc % SD_;
    const bf16* tp = t + ((size_t)bi * C_ + cOff + c) * N_;
    float w[KS * KS];
#pragma unroll
    for (int q = 0; q < KS * KS; q++) w[q] = dw[c * KS * KS + q];
    float* op = outp + ((size_t)bi * SD_ + c) * N_;
    const int P = KS / 2;
    for (int n = threadIdx.x; n < N_; n += 256) {
        int i = n >> 5, j = n & 31;
        float acc = 0.f;
#pragma unroll
        for (int di = 0; di < KS; di++) {
            int ii = i + di - P;
            if (ii < 0 || ii > 31) continue;
#pragma unroll
            for (int dj = 0; dj < KS; dj++) {
                int jj = j + dj - P;
                if (jj < 0 || jj > 31) continue;
                acc += bf2f(tp[ii * 32 + jj]) * w[di * KS + dj];
            }
        }
        op[n] = acc;
    }
}

template <int MODE>  // 0: BN+hswish -> th (bf16);  1: raw fp32 -> rawOut
__global__ void pw_kernel(const float* __restrict__ inp, const float* __restrict__ pw,
                          const float* __restrict__ g, const float* __restrict__ b,
                            const float* __restrict__ m, const float* __restrict__ v,
                          int cOff, bf16* __restrict__ th, float* __restrict__ rawOut) {
    int bo = blockIdx.x;
    int bi = bo / SD_, o = bo % SD_;
    __shared__ float wrow[SD_];
    for (int c = threadIdx.x; c < SD_; c += 256) wrow[c] = pw[o * SD_ + c];
    __syncthreads();
    const float* ip = inp + (size_t)bi * SD_ * N_;
    int t = threadIdx.x;
    float acc[4] = {0.f, 0.f, 0.f, 0.f};
    for (int c = 0; c < SD_; c++) {
        const float* row = ip + (size_t)c * N_;
        float wc = wrow[c];
#pragma unroll
        for (int r = 0; r < 4; r++) acc[r] += row[t + 256 * r] * wc;
    }
    if (MODE == 0) {
        float inv = g[o] * rsqrtf(v[o] + 1e-5f);
        float mm = m[o], bb = b[o];
        bf16* base = th + (size_t)bi * H_ * C_ * D_;
#pragma unroll
        for (int r = 0; r < 4; r++) {
            int n = t + 256 * r;
            float y = hswish((acc[r] - mm) * inv + bb);
            base[((n >> 7) * C_ + cOff + o) * D_ + (n & 127)] = f2bf(y);
        }
    } else {
        float* opr = rawOut + ((size_t)bi * SD_ + o) * N_;
#pragma unroll
        for (int r = 0; r < 4; r++) opr[t + 256 * r] = acc[r];
    }
}

__global__ void gn_stats_kernel(const float* __restrict__ tmp2, float* __restrict__ stats) {
    int bg = blockIdx.x;          // b*2 + grp
    int bi = bg >> 1, grp = bg & 1;
    const float* p = tmp2 + (size_t)bi * SD_ * N_ + (size_t)grp * 39 * N_;
    float s = 0.f, sq = 0.f;
    const int TOT = 39 * N_;
    for (int i = threadIdx.x; i < TOT; i += 256) { float f = p[i]; s += f; sq += f * f; }
    __shared__ float rs[256], rq[256];
    rs[threadIdx.x] = s; rq[threadIdx.x] = sq; __syncthreads();
    for (int o = 128; o > 0; o >>= 1) {
        if (threadIdx.x < o) { rs[threadIdx.x] += rs[threadIdx.x + o]; rq[threadIdx.x] += rq[threadIdx.x + o]; }
        __syncthreads();
    }
    if (threadIdx.x == 0) {
        float mu = rs[0] / (float)TOT;
        float var = rq[0] / (float)TOT - mu * mu;
        stats[bg * 2] = mu;
        stats[bg * 2 + 1] = rsqrtf(var + 1e-5f);
    }
}

__global__ void gn_apply_kernel(const float* __restrict__ tmp2, const float* __restrict__ stats,
                                const float* __restrict__ gg, const float* __restrict__ gb,
                                bf16* __restrict__ th) {
    int bc = blockIdx.x;
    int bi = bc / SD_, c = bc % SD_;
    int grp = c / 39;
    float mu = stats[(bi * 2 + grp) * 2];
    float rstd = stats[(bi * 2 + grp) * 2 + 1];
    float sc = gg[c] * rstd;
    float of = gb[c] - mu * sc;
    const float* p = tmp2 + ((size_t)bi * SD_ + c) * N_;
    bf16* base = th + (size_t)bi * H_ * C_ * D_;
    for (int n = threadIdx.x; n < N_; n += 256) {
        float y = hswish(p[n] * sc + of);
        base[((n >> 7) * C_ + 234 + c) * D_ + (n & 127)] = f2bf(y);
    }
}

// ---------------- attention (attn written fp32 directly into d_out) ---------
__global__ void attn_scores_kernel(const bf16* __restrict__ qh, const bf16* __restrict__ kh,
                                   float* __restrict__ attnOut) {
    int idx = blockIdx.x;              // (b*8+h)*312 + c
    int c = idx % C_;
    int bh = idx / C_;
    const bf16* qg = qh + ((size_t)bh * C_ + c) * D_;
    const bf16* kb = kh + (size_t)bh * C_ * D_;
    __shared__ float qrow[D_];
    __shared__ float s[C_];
    __shared__ float red[128];
    int t = threadIdx.x;               // 128 threads
    qrow[t] = bf2f(qg[t]);
    __syncthreads();
    const float scale = 0.08838834764831845f;  // 128^-0.5
    for (int k = t; k < C_; k += 128) {
        const bf16* kr = kb + (size_t)k * D_;
        float acc = 0.f;
#pragma unroll 8
        for (int dd = 0; dd < D_; dd++) acc += qrow[dd] * bf2f(kr[dd]);
        float ge = 0.5f * acc * (1.0f + erff(acc * 0.7071067811865475f));
        s[k] = ge * scale;
    }
    __syncthreads();
    float lm = -1e30f;
    for (int k = t; k < C_; k += 128) lm = fmaxf(lm, s[k]);
    red[t] = lm; __syncthreads();
    for (int o = 64; o > 0; o >>= 1) { if (t < o) red[t] = fmaxf(red[t], red[t + o]); __syncthreads(); }
    float mx = red[0];
    __syncthreads();
    float ls = 0.f;
    for (int k = t; k < C_; k += 128) { float e = expf(s[k] - mx); s[k] = e; ls += e; }
    red[t] = ls; __syncthreads();
    for (int o = 64; o > 0; o >>= 1) { if (t < o) red[t] += red[t + o]; __syncthreads(); }
    float inv = 1.0f / red[0];
    float* ao = attnOut + ((size_t)bh * C_ + c) * C_;
    for (int k = t; k < C_; k += 128) ao[k] = s[k] * inv;
}

__global__ void av_kernel(const float* __restrict__ attn, const bf16* __restrict__ vh,
                          bf16* __restrict__ ctx) {
    int idx = blockIdx.x;
    int c = idx % C_;
    int bh = idx / C_;
    int b = bh >> 3, h = bh & 7;
    __shared__ float arow[C_];
    int t = threadIdx.x;               // 128 threads (= dd)
    const float* ar = attn + ((size_t)bh * C_ + c) * C_;
    for (int k = t; k < C_; k += 128) arow[k] = ar[k];
    __syncthreads();
    const bf16* vb = vh + (size_t)bh * C_ * D_;
    float acc = 0.f;
    for (int k = 0; k < C_; k++) acc += arow[k] * bf2f(vb[(size_t)k * D_ + t]);
    // scrambled reshape: out2[b, h*39 + c/8, (c%8)*128 + dd]
    size_t oi = ((size_t)b * C_ + h * 39 + (c >> 3)) * N_ + ((c & 7) << 7) + t;
    ctx[oi] = f2bf(acc);
}

// ---------------- L2 row norm (fp32 out) -------------------------------------
__global__ void norm_kernel(const float* __restrict__ out3, float* __restrict__ outp) {
    int r = blockIdx.x;
    const float* p = out3 + (size_t)r * N_;
    float sq = 0.f;
    for (int i = threadIdx.x; i < N_; i += 256) { float f = p[i]; sq += f * f; }
    __shared__ float rq[256];
    rq[threadIdx.x] = sq; __syncthreads();
    for (int o = 128; o > 0; o >>= 1) {
        if (threadIdx.x < o) rq[threadIdx.x] += rq[threadIdx.x + o];
        __syncthreads();
    }
    float inv = 1.0f / fmaxf(sqrtf(rq[0]), 1e-12f);
    float* po = outp + (size_t)r * N_;
    for (int i = threadIdx.x; i < N_; i += 256) po[i] = p[i] * inv;
}

// ---------------- host orchestration ----------------------------------------
extern "C" void kernel_launch(void* const* d_in, const int* in_sizes, int n_in,
                              void* d_out, int out_size, void* d_ws, size_t ws_size,
                              hipStream_t stream) {
    const float* x      = (const float*)d_in[0];
    const float* ln_q_g = (const float*)d_in[3];
    const float* ln_q_b = (const float*)d_in[4];
    const float* ln_k_g = (const float*)d_in[5];
    const float* ln_k_b = (const float*)d_in[6];
    const float* ln_v_g = (const float*)d_in[7];
    const float* ln_v_b = (const float*)d_in[8];
    const float* w_q    = (const float*)d_in[9];
    const float* w_k    = (const float*)d_in[10];
    const float* w_v    = (const float*)d_in[11];
    const float* w_proj = (const float*)d_in[12];
    const float* b_proj = (const float*)d_in[13];
    const float* dw0    = (const float*)d_in[14];
    const float* pw0    = (const float*)d_in[15];
    const float* gn_g   = (const float*)d_in[16];
    const float* gn_b   = (const float*)d_in[17];
    const float* dw1    = (const float*)d_in[18];
    const float* pw1    = (const float*)d_in[19];
    const float* dw2    = (const float*)d_in[20];
    const float* pw2    = (const float*)d_in[21];
    const float* bn0_g  = (const float*)d_in[22];
    const float* bn0_b  = (const float*)d_in[23];
    const float* bn0_m  = (const float*)d_in[24];
    const float* bn0_v  = (const float*)d_in[25];
    const float* bn1_g  = (const float*)d_in[26];
    const float* bn1_b  = (const float*)d_in[27];
    const float* bn1_m  = (const float*)d_in[28];
    const float* bn1_v  = (const float*)d_in[29];
    const float* bn2_g  = (const float*)d_in[30];
    const float* bn2_b  = (const float*)d_in[31];
    const float* bn2_m  = (const float*)d_in[32];
    const float* bn2_v  = (const float*)d_in[33];

    char* ws = (char*)d_ws;
    size_t off = 0;
    auto alloc = [&](size_t bytes) {
        void* p = ws + off;
        off = (off + bytes + 255) & ~(size_t)255;
        return p;
    };
    const size_t BF_BYTES = (size_t)BC_ * N_ * sizeof(bf16);      // 19.5 MiB
    bf16*  xn   = (bf16*)alloc(BF_BYTES);
    bf16*  qb   = (bf16*)alloc(BF_BYTES);
    bf16*  kb   = (bf16*)alloc(BF_BYTES);
    bf16*  vb   = (bf16*)alloc(BF_BYTES);
    float* tmp1 = (float*)alloc((size_t)B_ * SD_ * N_ * sizeof(float));
    float* tmp2 = (float*)alloc((size_t)B_ * SD_ * N_ * sizeof(float));
    float* gnst = (float*)alloc(512);
    // buffer reuse after consumers finish (stream-ordered):
    bf16* qh  = xn;   // agg(q) output (xn dead after GEMMs)
    bf16* kh  = qb;   // agg(k) output (qb dead after agg(q))
    bf16* vh  = kb;   // agg(v) output (kb dead after agg(k))
    bf16* ctx = vb;   // attn@V output (vb dead after agg(v))
    // out3 (fp32, BC*N) aliases xn+qb: both dead after attn_scores/av consume qh/kh.
    float* out3 = (float*)xn;   // 2*BF_BYTES == BC_*N_*4 exactly

    float* out_main = (float*)d_out;                       // fp32 output!
    float* attn_out = out_main + (size_t)BC_ * N_;         // fp32 attn region

    dim3 gemm_grid(N_ / BN, BC_ / BM);  // (16, 156)

    // 1) shared LN stats -> xn (affine folded into GEMM A-load)
    hipLaunchKernelGGL(ln_kernel, dim3(BC_), dim3(256), 0, stream, x, xn);
    // 2) QKV GEMMs
    hipLaunchKernelGGL((gemm_kernel<false>), gemm_grid, dim3(256), 0, stream,
                       xn, ln_q_g, ln_q_b, w_q, (const float*)nullptr, (void*)qb, BC_, N_, N_);
    hipLaunchKernelGGL((gemm_kernel<false>), gemm_grid, dim3(256), 0, stream,
                       xn, ln_k_g, ln_k_b, w_k, (const float*)nullptr, (void*)kb, BC_, N_, N_);
    hipLaunchKernelGGL((gemm_kernel<false>), gemm_grid, dim3(256), 0, stream,
                       xn, ln_v_g, ln_v_b, w_v, (const float*)nullptr, (void*)vb, BC_, N_, N_);

    // 3) aggregator for each of q,k,v
    const bf16* tins[3] = {qb, kb, vb};
    bf16* thouts[3] = {qh, kh, vh};
    for (int i = 0; i < 3; i++) {
        const bf16* t = tins[i];
        bf16* th = thouts[i];
        dim3 g2496(B_ * SD_);
        hipLaunchKernelGGL(seg0_kernel, g2496, dim3(256), 0, stream,
                           t, th, bn0_g, bn0_b, bn0_m, bn0_v);
        // seg1: sepconv 3x3 (dw1/pw1) + bn1
        hipLaunchKernelGGL((dw_kernel<3>), g2496, dim3(256), 0, stream, t, SD_, dw1, tmp1);
        hipLaunchKernelGGL((pw_kernel<0>), g2496, dim3(256), 0, stream,
                           tmp1, pw1, bn1_g, bn1_b, bn1_m, bn1_v, SD_, th, (float*)nullptr);
        // seg2: sepconv 5x5 (dw2/pw2) + bn2
        hipLaunchKernelGGL((dw_kernel<5>), g2496, dim3(256), 0, stream, t, 2 * SD_, dw2, tmp1);
        hipLaunchKernelGGL((pw_kernel<0>), g2496, dim3(256), 0, stream,
                           tmp1, pw2, bn2_g, bn2_b, bn2_m, bn2_v, 2 * SD_, th, (float*)nullptr);
        // seg3: sepconv 3x3 (dw0/pw0) + GN(2 groups)
        hipLaunchKernelGGL((dw_kernel<3>), g2496, dim3(256), 0, stream, t, 3 * SD_, dw0, tmp1);
        hipLaunchKernelGGL((pw_kernel<1>), g2496, dim3(256), 0, stream,
                           tmp1, pw0, (const float*)nullptr, (const float*)nullptr,
                           (const float*)nullptr, (const float*)nullptr, 0, (bf16*)nullptr, tmp2);
        hipLaunchKernelGGL(gn_stats_kernel, dim3(B_ * 2), dim3(256), 0, stream, tmp2, gnst);
        hipLaunchKernelGGL(gn_apply_kernel, g2496, dim3(256), 0, stream, tmp2, gnst, gn_g, gn_b, th);
    }

    // 4) scores + gelu + softmax -> attn (fp32, directly into d_out tail)
    hipLaunchKernelGGL(attn_scores_kernel, dim3(BH_ * C_), dim3(128), 0, stream, qh, kh, attn_out);
    // 5) attn @ V -> ctx (scrambled (B,C,N) layout)
    hipLaunchKernelGGL(av_kernel, dim3(BH_ * C_), dim3(128), 0, stream, attn_out, vh, ctx);
    // 6) projection GEMM + bias -> fp32 (out3 aliases dead xn+qb region)
    hipLaunchKernelGGL((gemm_kernel<true>), gemm_grid, dim3(256), 0, stream,
                       ctx, (const float*)nullptr, (const float*)nullptr, w_proj, b_proj,
                       (void*)out3, BC_, N_, N_);
    // 7) L2 row normalization -> fp32 main output
    hipLaunchKernelGGL(norm_kernel, dim3(BC_), dim3(256), 0, stream, out3, out_main);
}

// Round 4
// 1684.940 us; speedup vs baseline: 2.5434x; 2.5434x over previous
//
#include <hip/hip_runtime.h>
#include <hip/hip_bf16.h>
#include <float.h>

typedef __hip_bfloat16 bf16;
typedef __attribute__((ext_vector_type(8))) __bf16 bfrag;   // MFMA A/B operand (4 VGPRs)
typedef __attribute__((ext_vector_type(4))) float f32x4;    // MFMA C/D operand

#define B_ 32
#define C_ 312
#define N_ 1024
#define H_ 8
#define D_ 128
#define SD_ 78
#define BC_ (B_ * C_)      // 9984
#define BH_ (B_ * H_)      // 256

__device__ __forceinline__ float bf2f(bf16 x) { return __bfloat162float(x); }
__device__ __forceinline__ bf16 f2bf(float x) { return __float2bfloat16(x); }
__device__ __forceinline__ float hswish(float x) {
    return x * fminf(fmaxf(x + 3.0f, 0.0f), 6.0f) * (1.0f / 6.0f);
}

// ---------------- LayerNorm (stats only; affine folded into GEMM A-load) ----
__global__ void ln_kernel(const float* __restrict__ x, bf16* __restrict__ xn) {
    int r = blockIdx.x;
    int t = threadIdx.x;
    const float* xr = x + (size_t)r * N_;
    float s = 0.f, sq = 0.f;
    for (int i = t; i < N_; i += 256) { float f = xr[i]; s += f; sq += f * f; }
    __shared__ float rs[256], rq[256];
    rs[t] = s; rq[t] = sq; __syncthreads();
    for (int o = 128; o > 0; o >>= 1) {
        if (t < o) { rs[t] += rs[t + o]; rq[t] += rq[t + o]; }
        __syncthreads();
    }
    float mu = rs[0] * (1.0f / N_);
    float var = rq[0] * (1.0f / N_) - mu * mu;
    float rstd = rsqrtf(var + 1e-5f);
    bf16* xo = xn + (size_t)r * N_;
    for (int i = t; i < N_; i += 256) xo[i] = f2bf((xr[i] - mu) * rstd);
}

// ---------------- MFMA GEMM: C[M,1024] = A' * W^T (+bias) -------------------
// A bf16 (M x 1024), A' = A*G + Bv per-column (optional), W fp32 (1024 x 1024)
// row-major (so W^T is NT-natural). BM=BN=128, BK=64, 256 threads (4 waves 2x2).
#define GLDA 72   // LDS row stride (bf16 elems): 64 + 8 pad -> bank-friendly
template <bool OUTF32>
__global__ __launch_bounds__(256) void mfma_gemm_kernel(
        const bf16* __restrict__ A_,
        const float* __restrict__ G,
        const float* __restrict__ Bv,
        const float* __restrict__ W,
        const float* __restrict__ bias,
        void* __restrict__ Cout) {
    const int K = 1024, Nout = 1024;
    __shared__ __bf16 sA[128 * GLDA];
    __shared__ __bf16 sB[128 * GLDA];
    const __bf16* A = reinterpret_cast<const __bf16*>(A_);

    int t = threadIdx.x;
    int lane = t & 63, wave = t >> 6;
    int wm = (wave >> 1) * 64, wn = (wave & 1) * 64;
    int quad = lane >> 4, l15 = lane & 15;
    int m0 = blockIdx.y * 128, n0 = blockIdx.x * 128;

    f32x4 acc[4][4];
#pragma unroll
    for (int i = 0; i < 4; i++)
#pragma unroll
        for (int j = 0; j < 4; j++) acc[i][j] = (f32x4)(0.f);

    for (int kt = 0; kt < 16; kt++) {
        int k0 = kt * 64;
        // stage A slab (128 rows x 64 k) as bf16 with optional LN affine
#pragma unroll
        for (int cc = 0; cc < 4; cc++) {
            int c = t + cc * 256;                  // 0..1023
            int row = c >> 3, seg = c & 7;
            bfrag av = *reinterpret_cast<const bfrag*>(A + (size_t)(m0 + row) * K + k0 + seg * 8);
            if (G) {
                bfrag bv2;
#pragma unroll
                for (int j = 0; j < 8; j++) {
                    float fa = (float)av[j];
                    bv2[j] = (__bf16)(fa * G[k0 + seg * 8 + j] + Bv[k0 + seg * 8 + j]);
                }
                av = bv2;
            }
            *reinterpret_cast<bfrag*>(&sA[row * GLDA + seg * 8]) = av;
        }
        // stage W slab (128 n-rows x 64 k) fp32 -> bf16
#pragma unroll
        for (int cc = 0; cc < 4; cc++) {
            int c = t + cc * 256;
            int row = c >> 3, seg = c & 7;
            const float* wp = W + (size_t)(n0 + row) * K + k0 + seg * 8;
            float4 w0 = *reinterpret_cast<const float4*>(wp);
            float4 w1 = *reinterpret_cast<const float4*>(wp + 4);
            bfrag bv2;
            bv2[0] = (__bf16)w0.x; bv2[1] = (__bf16)w0.y; bv2[2] = (__bf16)w0.z; bv2[3] = (__bf16)w0.w;
            bv2[4] = (__bf16)w1.x; bv2[5] = (__bf16)w1.y; bv2[6] = (__bf16)w1.z; bv2[7] = (__bf16)w1.w;
            *reinterpret_cast<bfrag*>(&sB[row * GLDA + seg * 8]) = bv2;
        }
        __syncthreads();
#pragma unroll
        for (int kk = 0; kk < 2; kk++) {
            bfrag af[4], bf[4];
#pragma unroll
            for (int mt = 0; mt < 4; mt++)
                af[mt] = *reinterpret_cast<const bfrag*>(&sA[(wm + mt * 16 + l15) * GLDA + kk * 32 + quad * 8]);
#pragma unroll
            for (int nt = 0; nt < 4; nt++)
                bf[nt] = *reinterpret_cast<const bfrag*>(&sB[(wn + nt * 16 + l15) * GLDA + kk * 32 + quad * 8]);
#pragma unroll
            for (int mt = 0; mt < 4; mt++)
#pragma unroll
                for (int nt = 0; nt < 4; nt++)
                    acc[mt][nt] = __builtin_amdgcn_mfma_f32_16x16x32_bf16(af[mt], bf[nt], acc[mt][nt], 0, 0, 0);
        }
        __syncthreads();
    }
    // epilogue: C/D layout col=lane&15, row=quad*4+reg
#pragma unroll
    for (int mt = 0; mt < 4; mt++) {
#pragma unroll
        for (int nt = 0; nt < 4; nt++) {
            int col = n0 + wn + nt * 16 + l15;
            float bb = bias ? bias[col] : 0.f;
#pragma unroll
            for (int r = 0; r < 4; r++) {
                int row = m0 + wm + mt * 16 + quad * 4 + r;
                float v = acc[mt][nt][r] + bb;
                if (OUTF32) ((float*)Cout)[(size_t)row * Nout + col] = v;
                else        ((bf16*)Cout)[(size_t)row * Nout + col] = f2bf(v);
            }
        }
    }
}

// ---------------- aggregator pieces -----------------------------------------
__global__ void seg0_kernel(const bf16* __restrict__ t, bf16* __restrict__ th,
                            const float* __restrict__ g, const float* __restrict__ b,
                            const float* __restrict__ m, const float* __restrict__ v) {
    int bc = blockIdx.x;
    int bi = bc / SD_, c = bc % SD_;
    float inv = g[c] * rsqrtf(v[c] + 1e-5f);
    float mm = m[c], bb = b[c];
    const bf16* tp = t + ((size_t)bi * C_ + c) * N_;
    bf16* base = th + (size_t)bi * H_ * C_ * D_;
    for (int n = threadIdx.x; n < N_; n += 256) {
        float y = hswish((bf2f(tp[n]) - mm) * inv + bb);
        base[((n >> 7) * C_ + c) * D_ + (n & 127)] = f2bf(y);
    }
}

template <int KS>
__global__ void dw_kernel(const bf16* __restrict__ t, int cOff,
                          const float* __restrict__ dw, float* __restrict__ outp) {
    int bc = blockIdx.x;
    int bi = bc / SD_, c = bc % SD_;
    const bf16* tp = t + ((size_t)bi * C_ + cOff + c) * N_;
    float w[KS * KS];
#pragma unroll
    for (int q = 0; q < KS * KS; q++) w[q] = dw[c * KS * KS + q];
    float* op = outp + ((size_t)bi * SD_ + c) * N_;
    const int P = KS / 2;
    for (int n = threadIdx.x; n < N_; n += 256) {
        int i = n >> 5, j = n & 31;
        float acc = 0.f;
#pragma unroll
        for (int di = 0; di < KS; di++) {
            int ii = i + di - P;
            if (ii < 0 || ii > 31) continue;
#pragma unroll
            for (int dj = 0; dj < KS; dj++) {
                int jj = j + dj - P;
                if (jj < 0 || jj > 31) continue;
                acc += bf2f(tp[ii * 32 + jj]) * w[di * KS + dj];
            }
        }
        op[n] = acc;
    }
}

template <int MODE>
__global__ void pw_kernel(const float* __restrict__ inp, const float* __restrict__ pw,
                          const float* __restrict__ g, const float* __restrict__ b,
                          const float* __restrict__ m, const float* __restrict__ v,
                          int cOff, bf16* __restrict__ th, float* __restrict__ rawOut) {
    int bo = blockIdx.x;
    int bi = bo / SD_, o = bo % SD_;
    __shared__ float wrow[SD_];
    for (int c = threadIdx.x; c < SD_; c += 256) wrow[c] = pw[o * SD_ + c];
    __syncthreads();
    const float* ip = inp + (size_t)bi * SD_ * N_;
    int t = threadIdx.x;
    float acc[4] = {0.f, 0.f, 0.f, 0.f};
    for (int c = 0; c < SD_; c++) {
        const float* row = ip + (size_t)c * N_;
        float wc = wrow[c];
#pragma unroll
        for (int r = 0; r < 4; r++) acc[r] += row[t + 256 * r] * wc;
    }
    if (MODE == 0) {
        float inv = g[o] * rsqrtf(v[o] + 1e-5f);
        float mm = m[o], bb = b[o];
        bf16* base = th + (size_t)bi * H_ * C_ * D_;
#pragma unroll
        for (int r = 0; r < 4; r++) {
            int n = t + 256 * r;
            float y = hswish((acc[r] - mm) * inv + bb);
            base[((n >> 7) * C_ + cOff + o) * D_ + (n & 127)] = f2bf(y);
        }
    } else {
        float* opr = rawOut + ((size_t)bi * SD_ + o) * N_;
#pragma unroll
        for (int r = 0; r < 4; r++) opr[t + 256 * r] = acc[r];
    }
}

__global__ void gn_stats_kernel(const float* __restrict__ tmp2, float* __restrict__ stats) {
    int bg = blockIdx.x;
    int bi = bg >> 1, grp = bg & 1;
    const float* p = tmp2 + (size_t)bi * SD_ * N_ + (size_t)grp * 39 * N_;
    float s = 0.f, sq = 0.f;
    const int TOT = 39 * N_;
    for (int i = threadIdx.x; i < TOT; i += 256) { float f = p[i]; s += f; sq += f * f; }
    __shared__ float rs[256], rq[256];
    rs[threadIdx.x] = s; rq[threadIdx.x] = sq; __syncthreads();
    for (int o = 128; o > 0; o >>= 1) {
        if (threadIdx.x < o) { rs[threadIdx.x] += rs[threadIdx.x + o]; rq[threadIdx.x] += rq[threadIdx.x + o]; }
        __syncthreads();
    }
    if (threadIdx.x == 0) {
        float mu = rs[0] / (float)TOT;
        float var = rq[0] / (float)TOT - mu * mu;
        stats[bg * 2] = mu;
        stats[bg * 2 + 1] = rsqrtf(var + 1e-5f);
    }
}

__global__ void gn_apply_kernel(const float* __restrict__ tmp2, const float* __restrict__ stats,
                                const float* __restrict__ gg, const float* __restrict__ gb,
                                bf16* __restrict__ th) {
    int bc = blockIdx.x;
    int bi = bc / SD_, c = bc % SD_;
    int grp = c / 39;
    float mu = stats[(bi * 2 + grp) * 2];
    float rstd = stats[(bi * 2 + grp) * 2 + 1];
    float sc = gg[c] * rstd;
    float of = gb[c] - mu * sc;
    const float* p = tmp2 + ((size_t)bi * SD_ + c) * N_;
    bf16* base = th + (size_t)bi * H_ * C_ * D_;
    for (int n = threadIdx.x; n < N_; n += 256) {
        float y = hswish(p[n] * sc + of);
        base[((n >> 7) * C_ + 234 + c) * D_ + (n & 127)] = f2bf(y);
    }
}

// ---- MFMA scores + GELU + scale + softmax, fused. One block = (bh, 64-row strip).
// Q strip staged once; K staged in two 160-row halves (LDS < 64 KB).
#define SLDA 136   // LDS row stride (bf16): 128 + 8
__global__ __launch_bounds__(256) void attn_mfma_kernel(
        const bf16* __restrict__ qh_, const bf16* __restrict__ kh_,
        float* __restrict__ attnOut) {
    __shared__ __bf16 sQ[64 * SLDA];    // 17408 B
    __shared__ __bf16 sK[160 * SLDA];   // 43520 B
    const __bf16* qh = reinterpret_cast<const __bf16*>(qh_);
    const __bf16* kh = reinterpret_cast<const __bf16*>(kh_);

    int strip = blockIdx.x;            // 0..4 (rows strip*64 .. +63)
    int bh = blockIdx.y;               // 0..255
    int t = threadIdx.x;
    int lane = t & 63, wave = t >> 6;
    int quad = lane >> 4, l15 = lane & 15;

    // stage Q strip: 64 rows x 128 (clamp source row to 311)
#pragma unroll
    for (int cc = 0; cc < 4; cc++) {
        int c = t + cc * 256;                 // 0..1023 ; row=c>>4, seg=c&15
        int row = c >> 4, seg = c & 15;
        int src = strip * 64 + row; if (src > 311) src = 311;
        bfrag v = *reinterpret_cast<const bfrag*>(qh + ((size_t)bh * C_ + src) * D_ + seg * 8);
        *reinterpret_cast<bfrag*>(&sQ[row * SLDA + seg * 8]) = v;
    }
    f32x4 acc[20];
#pragma unroll
    for (int i = 0; i < 20; i++) acc[i] = (f32x4)(0.f);

    bfrag af[4];
    bool afLoaded = false;

    for (int half = 0; half < 2; half++) {
        // stage K rows [half*160, half*160+160); zero rows >= 312
        for (int cc = 0; cc < 10; cc++) {
            int c = t + cc * 256;             // 0..2559 ; row=c>>4, seg=c&15
            int row = c >> 4, seg = c & 15;
            int src = half * 160 + row;
            bfrag v;
            if (src < C_) {
                v = *reinterpret_cast<const bfrag*>(kh + ((size_t)bh * C_ + src) * D_ + seg * 8);
            } else {
#pragma unroll
                for (int j = 0; j < 8; j++) v[j] = (__bf16)0.f;
            }
            *reinterpret_cast<bfrag*>(&sK[row * SLDA + seg * 8]) = v;
        }
        __syncthreads();
        if (!afLoaded) {
            // A-frags for this wave's 16 rows, all 4 k-steps (kept in regs)
#pragma unroll
            for (int ks = 0; ks < 4; ks++)
                af[ks] = *reinterpret_cast<const bfrag*>(&sQ[(wave * 16 + l15) * SLDA + ks * 32 + quad * 8]);
            afLoaded = true;
        }
#pragma unroll
        for (int ks = 0; ks < 4; ks++) {
#pragma unroll
            for (int nt = 0; nt < 10; nt++) {
                bfrag bf = *reinterpret_cast<const bfrag*>(&sK[(nt * 16 + l15) * SLDA + ks * 32 + quad * 8]);
                acc[half * 10 + nt] = __builtin_amdgcn_mfma_f32_16x16x32_bf16(af[ks], bf, acc[half * 10 + nt], 0, 0, 0);
            }
        }
        __syncthreads();
    }

    // epilogue: gelu -> *scale -> mask pad cols -> softmax over 312 cols
    const float scale = 0.08838834764831845f;   // 128^-0.5
    const float inv_sqrt2 = 0.7071067811865475f;
#pragma unroll
    for (int nt = 0; nt < 20; nt++) {
        int col = nt * 16 + l15;
#pragma unroll
        for (int r = 0; r < 4; r++) {
            float v = acc[nt][r];
            float ge = 0.5f * v * (1.0f + erff(v * inv_sqrt2));
            float s = ge * scale;
            if (col >= C_) s = -FLT_MAX;
            acc[nt][r] = s;
        }
    }
    // per-row reduce: rows live at fixed (quad, reg) across 16 lanes x 20 tiles
    float mx[4], sm[4];
#pragma unroll
    for (int r = 0; r < 4; r++) {
        float m = -FLT_MAX;
#pragma unroll
        for (int nt = 0; nt < 20; nt++) m = fmaxf(m, acc[nt][r]);
        for (int o = 1; o < 16; o <<= 1) m = fmaxf(m, __shfl_xor(m, o));
        mx[r] = m;
    }
#pragma unroll
    for (int r = 0; r < 4; r++) {
        float s = 0.f;
#pragma unroll
        for (int nt = 0; nt < 20; nt++) {
            float e = __expf(acc[nt][r] - mx[r]);
            acc[nt][r] = e;
            s += e;
        }
        for (int o = 1; o < 16; o <<= 1) s += __shfl_xor(s, o);
        sm[r] = 1.0f / s;
    }
    // write normalized attn
#pragma unroll
    for (int r = 0; r < 4; r++) {
        int row = strip * 64 + wave * 16 + quad * 4 + r;
        if (row >= C_) continue;
        float* ao = attnOut + ((size_t)bh * C_ + row) * C_;
#pragma unroll
        for (int nt = 0; nt < 20; nt++) {
            int col = nt * 16 + l15;
            if (col < C_) ao[col] = acc[nt][r] * sm[r];
        }
    }
}

__global__ void av_kernel(const float* __restrict__ attn, const bf16* __restrict__ vh,
                          bf16* __restrict__ ctx) {
    int idx = blockIdx.x;
    int c = idx % C_;
    int bh = idx / C_;
    int b = bh >> 3, h = bh & 7;
    __shared__ float arow[C_];
    int t = threadIdx.x;               // 128 threads (= dd)
    const float* ar = attn + ((size_t)bh * C_ + c) * C_;
    for (int k = t; k < C_; k += 128) arow[k] = ar[k];
    __syncthreads();
    const bf16* vb = vh + (size_t)bh * C_ * D_;
    float acc = 0.f;
    for (int k = 0; k < C_; k++) acc += arow[k] * bf2f(vb[(size_t)k * D_ + t]);
    size_t oi = ((size_t)b * C_ + h * 39 + (c >> 3)) * N_ + ((c & 7) << 7) + t;
    ctx[oi] = f2bf(acc);
}

// ---------------- L2 row norm (fp32 out) -------------------------------------
__global__ void norm_kernel(const float* __restrict__ out3, float* __restrict__ outp) {
    int r = blockIdx.x;
    const float* p = out3 + (size_t)r * N_;
    float sq = 0.f;
    for (int i = threadIdx.x; i < N_; i += 256) { float f = p[i]; sq += f * f; }
    __shared__ float rq[256];
    rq[threadIdx.x] = sq; __syncthreads();
    for (int o = 128; o > 0; o >>= 1) {
        if (threadIdx.x < o) rq[threadIdx.x] += rq[threadIdx.x + o];
        __syncthreads();
    }
    float inv = 1.0f / fmaxf(sqrtf(rq[0]), 1e-12f);
    float* po = outp + (size_t)r * N_;
    for (int i = threadIdx.x; i < N_; i += 256) po[i] = p[i] * inv;
}

// ---------------- host orchestration ----------------------------------------
extern "C" void kernel_launch(void* const* d_in, const int* in_sizes, int n_in,
                              void* d_out, int out_size, void* d_ws, size_t ws_size,
                              hipStream_t stream) {
    const float* x      = (const float*)d_in[0];
    const float* ln_q_g = (const float*)d_in[3];
    const float* ln_q_b = (const float*)d_in[4];
    const float* ln_k_g = (const float*)d_in[5];
    const float* ln_k_b = (const float*)d_in[6];
    const float* ln_v_g = (const float*)d_in[7];
    const float* ln_v_b = (const float*)d_in[8];
    const float* w_q    = (const float*)d_in[9];
    const float* w_k    = (const float*)d_in[10];
    const float* w_v    = (const float*)d_in[11];
    const float* w_proj = (const float*)d_in[12];
    const float* b_proj = (const float*)d_in[13];
    const float* dw0    = (const float*)d_in[14];
    const float* pw0    = (const float*)d_in[15];
    const float* gn_g   = (const float*)d_in[16];
    const float* gn_b   = (const float*)d_in[17];
    const float* dw1    = (const float*)d_in[18];
    const float* pw1    = (const float*)d_in[19];
    const float* dw2    = (const float*)d_in[20];
    const float* pw2    = (const float*)d_in[21];
    const float* bn0_g  = (const float*)d_in[22];
    const float* bn0_b  = (const float*)d_in[23];
    const float* bn0_m  = (const float*)d_in[24];
    const float* bn0_v  = (const float*)d_in[25];
    const float* bn1_g  = (const float*)d_in[26];
    const float* bn1_b  = (const float*)d_in[27];
    const float* bn1_m  = (const float*)d_in[28];
    const float* bn1_v  = (const float*)d_in[29];
    const float* bn2_g  = (const float*)d_in[30];
    const float* bn2_b  = (const float*)d_in[31];
    const float* bn2_m  = (const float*)d_in[32];
    const float* bn2_v  = (const float*)d_in[33];

    char* ws = (char*)d_ws;
    size_t off = 0;
    auto alloc = [&](size_t bytes) {
        void* p = ws + off;
        off = (off + bytes + 255) & ~(size_t)255;
        return p;
    };
    const size_t BF_BYTES = (size_t)BC_ * N_ * sizeof(bf16);
    bf16*  xn   = (bf16*)alloc(BF_BYTES);
    bf16*  qb   = (bf16*)alloc(BF_BYTES);
    bf16*  kb   = (bf16*)alloc(BF_BYTES);
    bf16*  vb   = (bf16*)alloc(BF_BYTES);
    float* tmp1 = (float*)alloc((size_t)B_ * SD_ * N_ * sizeof(float));
    float* tmp2 = (float*)alloc((size_t)B_ * SD_ * N_ * sizeof(float));
    float* gnst = (float*)alloc(512);
    bf16* qh  = xn;
    bf16* kh  = qb;
    bf16* vh  = kb;
    bf16* ctx = vb;
    float* out3 = (float*)xn;   // aliases xn+qb (dead after attn/av)

    float* out_main = (float*)d_out;
    float* attn_out = out_main + (size_t)BC_ * N_;

    dim3 gemm_grid(8, 78);   // N/128, M/128

    // 1) shared LN stats -> xn
    hipLaunchKernelGGL(ln_kernel, dim3(BC_), dim3(256), 0, stream, x, xn);
    // 2) QKV GEMMs (MFMA)
    hipLaunchKernelGGL((mfma_gemm_kernel<false>), gemm_grid, dim3(256), 0, stream,
                       xn, ln_q_g, ln_q_b, w_q, (const float*)nullptr, (void*)qb);
    hipLaunchKernelGGL((mfma_gemm_kernel<false>), gemm_grid, dim3(256), 0, stream,
                       xn, ln_k_g, ln_k_b, w_k, (const float*)nullptr, (void*)kb);
    hipLaunchKernelGGL((mfma_gemm_kernel<false>), gemm_grid, dim3(256), 0, stream,
                       xn, ln_v_g, ln_v_b, w_v, (const float*)nullptr, (void*)vb);

    // 3) aggregator for each of q,k,v
    const bf16* tins[3] = {qb, kb, vb};
    bf16* thouts[3] = {qh, kh, vh};
    for (int i = 0; i < 3; i++) {
        const bf16* t = tins[i];
        bf16* th = thouts[i];
        dim3 g2496(B_ * SD_);
        hipLaunchKernelGGL(seg0_kernel, g2496, dim3(256), 0, stream,
                           t, th, bn0_g, bn0_b, bn0_m, bn0_v);
        hipLaunchKernelGGL((dw_kernel<3>), g2496, dim3(256), 0, stream, t, SD_, dw1, tmp1);
        hipLaunchKernelGGL((pw_kernel<0>), g2496, dim3(256), 0, stream,
                           tmp1, pw1, bn1_g, bn1_b, bn1_m, bn1_v, SD_, th, (float*)nullptr);
        hipLaunchKernelGGL((dw_kernel<5>), g2496, dim3(256), 0, stream, t, 2 * SD_, dw2, tmp1);
        hipLaunchKernelGGL((pw_kernel<0>), g2496, dim3(256), 0, stream,
                           tmp1, pw2, bn2_g, bn2_b, bn2_m, bn2_v, 2 * SD_, th, (float*)nullptr);
        hipLaunchKernelGGL((dw_kernel<3>), g2496, dim3(256), 0, stream, t, 3 * SD_, dw0, tmp1);
        hipLaunchKernelGGL((pw_kernel<1>), g2496, dim3(256), 0, stream,
                           tmp1, pw0, (const float*)nullptr, (const float*)nullptr,
                           (const float*)nullptr, (const float*)nullptr, 0, (bf16*)nullptr, tmp2);
        hipLaunchKernelGGL(gn_stats_kernel, dim3(B_ * 2), dim3(256), 0, stream, tmp2, gnst);
        hipLaunchKernelGGL(gn_apply_kernel, g2496, dim3(256), 0, stream, tmp2, gnst, gn_g, gn_b, th);
    }

    // 4) fused MFMA scores + gelu + scale + softmax -> attn (fp32 in d_out tail)
    hipLaunchKernelGGL(attn_mfma_kernel, dim3(5, BH_), dim3(256), 0, stream, qh, kh, attn_out);
    // 5) attn @ V -> ctx (scrambled (B,C,N) layout)
    hipLaunchKernelGGL(av_kernel, dim3(BH_ * C_), dim3(128), 0, stream, attn_out, vh, ctx);
    // 6) projection GEMM + bias -> fp32 (MFMA)
    hipLaunchKernelGGL((mfma_gemm_kernel<true>), gemm_grid, dim3(256), 0, stream,
                       ctx, (const float*)nullptr, (const float*)nullptr, w_proj, b_proj,
                       (void*)out3);
    // 7) L2 row normalization -> fp32 main output
    hipLaunchKernelGGL(norm_kernel, dim3(BC_), dim3(256), 0, stream, out3, out_main);
}

// Round 5
// 1440.879 us; speedup vs baseline: 2.9742x; 1.1694x over previous
//
#include <hip/hip_runtime.h>
#include <hip/hip_bf16.h>
#include <float.h>

typedef __hip_bfloat16 bf16;
typedef __attribute__((ext_vector_type(8))) __bf16 bfrag;   // MFMA A/B operand (4 VGPRs)
typedef __attribute__((ext_vector_type(4))) float f32x4;    // MFMA C/D operand

#define B_ 32
#define C_ 312
#define N_ 1024
#define H_ 8
#define D_ 128
#define SD_ 78
#define BC_ (B_ * C_)      // 9984
#define BH_ (B_ * H_)      // 256

__device__ __forceinline__ float bf2f(bf16 x) { return __bfloat162float(x); }
__device__ __forceinline__ bf16 f2bf(float x) { return __float2bfloat16(x); }
__device__ __forceinline__ float hswish(float x) {
    return x * fminf(fmaxf(x + 3.0f, 0.0f), 6.0f) * (1.0f / 6.0f);
}

// ---------------- LayerNorm (stats only; affine folded into GEMM A-load) ----
__global__ void ln_kernel(const float* __restrict__ x, bf16* __restrict__ xn) {
    int r = blockIdx.x;
    int t = threadIdx.x;
    const float* xr = x + (size_t)r * N_;
    float s = 0.f, sq = 0.f;
    for (int i = t; i < N_; i += 256) { float f = xr[i]; s += f; sq += f * f; }
    __shared__ float rs[256], rq[256];
    rs[t] = s; rq[t] = sq; __syncthreads();
    for (int o = 128; o > 0; o >>= 1) {
        if (t < o) { rs[t] += rs[t + o]; rq[t] += rq[t + o]; }
        __syncthreads();
    }
    float mu = rs[0] * (1.0f / N_);
    float var = rq[0] * (1.0f / N_) - mu * mu;
    float rstd = rsqrtf(var + 1e-5f);
    bf16* xo = xn + (size_t)r * N_;
    for (int i = t; i < N_; i += 256) xo[i] = f2bf((xr[i] - mu) * rstd);
}

// ---------------- MFMA GEMM: C[M,1024] = A' * W^T (+bias) -------------------
#define GLDA 72   // LDS row stride (bf16 elems): 64 + 8 pad
template <bool OUTF32>
__global__ __launch_bounds__(256) void mfma_gemm_kernel(
        const bf16* __restrict__ A_,
        const float* __restrict__ G,
        const float* __restrict__ Bv,
        const float* __restrict__ W,
        const float* __restrict__ bias,
        void* __restrict__ Cout) {
    const int K = 1024, Nout = 1024;
    __shared__ __bf16 sA[128 * GLDA];
    __shared__ __bf16 sB[128 * GLDA];
    const __bf16* A = reinterpret_cast<const __bf16*>(A_);

    int t = threadIdx.x;
    int lane = t & 63, wave = t >> 6;
    int wm = (wave >> 1) * 64, wn = (wave & 1) * 64;
    int quad = lane >> 4, l15 = lane & 15;
    int m0 = blockIdx.y * 128, n0 = blockIdx.x * 128;

    f32x4 acc[4][4];
#pragma unroll
    for (int i = 0; i < 4; i++)
#pragma unroll
        for (int j = 0; j < 4; j++) acc[i][j] = (f32x4)(0.f);

    for (int kt = 0; kt < 16; kt++) {
        int k0 = kt * 64;
#pragma unroll
        for (int cc = 0; cc < 4; cc++) {
            int c = t + cc * 256;
            int row = c >> 3, seg = c & 7;
            bfrag av = *reinterpret_cast<const bfrag*>(A + (size_t)(m0 + row) * K + k0 + seg * 8);
            if (G) {
                bfrag bv2;
#pragma unroll
                for (int j = 0; j < 8; j++) {
                    float fa = (float)av[j];
                    bv2[j] = (__bf16)(fa * G[k0 + seg * 8 + j] + Bv[k0 + seg * 8 + j]);
                }
                av = bv2;
            }
            *reinterpret_cast<bfrag*>(&sA[row * GLDA + seg * 8]) = av;
        }
#pragma unroll
        for (int cc = 0; cc < 4; cc++) {
            int c = t + cc * 256;
            int row = c >> 3, seg = c & 7;
            const float* wp = W + (size_t)(n0 + row) * K + k0 + seg * 8;
            float4 w0 = *reinterpret_cast<const float4*>(wp);
            float4 w1 = *reinterpret_cast<const float4*>(wp + 4);
            bfrag bv2;
            bv2[0] = (__bf16)w0.x; bv2[1] = (__bf16)w0.y; bv2[2] = (__bf16)w0.z; bv2[3] = (__bf16)w0.w;
            bv2[4] = (__bf16)w1.x; bv2[5] = (__bf16)w1.y; bv2[6] = (__bf16)w1.z; bv2[7] = (__bf16)w1.w;
            *reinterpret_cast<bfrag*>(&sB[row * GLDA + seg * 8]) = bv2;
        }
        __syncthreads();
#pragma unroll
        for (int kk = 0; kk < 2; kk++) {
            bfrag af[4], bf[4];
#pragma unroll
            for (int mt = 0; mt < 4; mt++)
                af[mt] = *reinterpret_cast<const bfrag*>(&sA[(wm + mt * 16 + l15) * GLDA + kk * 32 + quad * 8]);
#pragma unroll
            for (int nt = 0; nt < 4; nt++)
                bf[nt] = *reinterpret_cast<const bfrag*>(&sB[(wn + nt * 16 + l15) * GLDA + kk * 32 + quad * 8]);
#pragma unroll
            for (int mt = 0; mt < 4; mt++)
#pragma unroll
                for (int nt = 0; nt < 4; nt++)
                    acc[mt][nt] = __builtin_amdgcn_mfma_f32_16x16x32_bf16(af[mt], bf[nt], acc[mt][nt], 0, 0, 0);
        }
        __syncthreads();
    }
#pragma unroll
    for (int mt = 0; mt < 4; mt++) {
#pragma unroll
        for (int nt = 0; nt < 4; nt++) {
            int col = n0 + wn + nt * 16 + l15;
            float bb = bias ? bias[col] : 0.f;
#pragma unroll
            for (int r = 0; r < 4; r++) {
                int row = m0 + wm + mt * 16 + quad * 4 + r;
                float v = acc[mt][nt][r] + bb;
                if (OUTF32) ((float*)Cout)[(size_t)row * Nout + col] = v;
                else        ((bf16*)Cout)[(size_t)row * Nout + col] = f2bf(v);
            }
        }
    }
}

// ---------------- aggregator pieces -----------------------------------------
__global__ void seg0_kernel(const bf16* __restrict__ t, bf16* __restrict__ th,
                            const float* __restrict__ g, const float* __restrict__ b,
                            const float* __restrict__ m, const float* __restrict__ v) {
    int bc = blockIdx.x;
    int bi = bc / SD_, c = bc % SD_;
    float inv = g[c] * rsqrtf(v[c] + 1e-5f);
    float mm = m[c], bb = b[c];
    const bf16* tp = t + ((size_t)bi * C_ + c) * N_;
    bf16* base = th + (size_t)bi * H_ * C_ * D_;
    for (int n = threadIdx.x; n < N_; n += 256) {
        float y = hswish((bf2f(tp[n]) - mm) * inv + bb);
        base[((n >> 7) * C_ + c) * D_ + (n & 127)] = f2bf(y);
    }
}

template <int KS>
__global__ void dw_kernel(const bf16* __restrict__ t, int cOff,
                          const float* __restrict__ dw, float* __restrict__ outp) {
    int bc = blockIdx.x;
    int bi = bc / SD_, c = bc % SD_;
    const bf16* tp = t + ((size_t)bi * C_ + cOff + c) * N_;
    float w[KS * KS];
#pragma unroll
    for (int q = 0; q < KS * KS; q++) w[q] = dw[c * KS * KS + q];
    float* op = outp + ((size_t)bi * SD_ + c) * N_;
    const int P = KS / 2;
    for (int n = threadIdx.x; n < N_; n += 256) {
        int i = n >> 5, j = n & 31;
        float acc = 0.f;
#pragma unroll
        for (int di = 0; di < KS; di++) {
            int ii = i + di - P;
            if (ii < 0 || ii > 31) continue;
#pragma unroll
            for (int dj = 0; dj < KS; dj++) {
                int jj = j + dj - P;
                if (jj < 0 || jj > 31) continue;
                acc += bf2f(tp[ii * 32 + jj]) * w[di * KS + dj];
            }
        }
        op[n] = acc;
    }
}

template <int MODE>
__global__ void pw_kernel(const float* __restrict__ inp, const float* __restrict__ pw,
                          const float* __restrict__ g, const float* __restrict__ b,
                          const float* __restrict__ m, const float* __restrict__ v,
                          int cOff, bf16* __restrict__ th, float* __restrict__ rawOut) {
    int bo = blockIdx.x;
    int bi = bo / SD_, o = bo % SD_;
    __shared__ float wrow[SD_];
    for (int c = threadIdx.x; c < SD_; c += 256) wrow[c] = pw[o * SD_ + c];
    __syncthreads();
    const float* ip = inp + (size_t)bi * SD_ * N_;
    int t = threadIdx.x;
    float acc[4] = {0.f, 0.f, 0.f, 0.f};
    for (int c = 0; c < SD_; c++) {
        const float* row = ip + (size_t)c * N_;
        float wc = wrow[c];
#pragma unroll
        for (int r = 0; r < 4; r++) acc[r] += row[t + 256 * r] * wc;
    }
    if (MODE == 0) {
        float inv = g[o] * rsqrtf(v[o] + 1e-5f);
        float mm = m[o], bb = b[o];
        bf16* base = th + (size_t)bi * H_ * C_ * D_;
#pragma unroll
        for (int r = 0; r < 4; r++) {
            int n = t + 256 * r;
            float y = hswish((acc[r] - mm) * inv + bb);
            base[((n >> 7) * C_ + cOff + o) * D_ + (n & 127)] = f2bf(y);
        }
    } else {
        float* opr = rawOut + ((size_t)bi * SD_ + o) * N_;
#pragma unroll
        for (int r = 0; r < 4; r++) opr[t + 256 * r] = acc[r];
    }
}

__global__ void gn_stats_kernel(const float* __restrict__ tmp2, float* __restrict__ stats) {
    int bg = blockIdx.x;
    int bi = bg >> 1, grp = bg & 1;
    const float* p = tmp2 + (size_t)bi * SD_ * N_ + (size_t)grp * 39 * N_;
    float s = 0.f, sq = 0.f;
    const int TOT = 39 * N_;
    for (int i = threadIdx.x; i < TOT; i += 256) { float f = p[i]; s += f; sq += f * f; }
    __shared__ float rs[256], rq[256];
    rs[threadIdx.x] = s; rq[threadIdx.x] = sq; __syncthreads();
    for (int o = 128; o > 0; o >>= 1) {
        if (threadIdx.x < o) { rs[threadIdx.x] += rs[threadIdx.x + o]; rq[threadIdx.x] += rq[threadIdx.x + o]; }
        __syncthreads();
    }
    if (threadIdx.x == 0) {
        float mu = rs[0] / (float)TOT;
        float var = rq[0] / (float)TOT - mu * mu;
        stats[bg * 2] = mu;
        stats[bg * 2 + 1] = rsqrtf(var + 1e-5f);
    }
}

__global__ void gn_apply_kernel(const float* __restrict__ tmp2, const float* __restrict__ stats,
                                const float* __restrict__ gg, const float* __restrict__ gb,
                                bf16* __restrict__ th) {
    int bc = blockIdx.x;
    int bi = bc / SD_, c = bc % SD_;
    int grp = c / 39;
    float mu = stats[(bi * 2 + grp) * 2];
    float rstd = stats[(bi * 2 + grp) * 2 + 1];
    float sc = gg[c] * rstd;
    float of = gb[c] - mu * sc;
    const float* p = tmp2 + ((size_t)bi * SD_ + c) * N_;
    bf16* base = th + (size_t)bi * H_ * C_ * D_;
    for (int n = threadIdx.x; n < N_; n += 256) {
        float y = hswish(p[n] * sc + of);
        base[((n >> 7) * C_ + 234 + c) * D_ + (n & 127)] = f2bf(y);
    }
}

// ---- MFMA scores + GELU + scale + softmax, fused ---------------------------
#define SLDA 136
__global__ __launch_bounds__(256) void attn_mfma_kernel(
        const bf16* __restrict__ qh_, const bf16* __restrict__ kh_,
        float* __restrict__ attnOut) {
    __shared__ __bf16 sQ[64 * SLDA];
    __shared__ __bf16 sK[160 * SLDA];
    const __bf16* qh = reinterpret_cast<const __bf16*>(qh_);
    const __bf16* kh = reinterpret_cast<const __bf16*>(kh_);

    int strip = blockIdx.x;
    int bh = blockIdx.y;
    int t = threadIdx.x;
    int lane = t & 63, wave = t >> 6;
    int quad = lane >> 4, l15 = lane & 15;

#pragma unroll
    for (int cc = 0; cc < 4; cc++) {
        int c = t + cc * 256;
        int row = c >> 4, seg = c & 15;
        int src = strip * 64 + row; if (src > 311) src = 311;
        bfrag v = *reinterpret_cast<const bfrag*>(qh + ((size_t)bh * C_ + src) * D_ + seg * 8);
        *reinterpret_cast<bfrag*>(&sQ[row * SLDA + seg * 8]) = v;
    }
    f32x4 acc[20];
#pragma unroll
    for (int i = 0; i < 20; i++) acc[i] = (f32x4)(0.f);

    bfrag af[4];
    bool afLoaded = false;

    for (int half = 0; half < 2; half++) {
        for (int cc = 0; cc < 10; cc++) {
            int c = t + cc * 256;
            int row = c >> 4, seg = c & 15;
            int src = half * 160 + row;
            bfrag v;
            if (src < C_) {
                v = *reinterpret_cast<const bfrag*>(kh + ((size_t)bh * C_ + src) * D_ + seg * 8);
            } else {
#pragma unroll
                for (int j = 0; j < 8; j++) v[j] = (__bf16)0.f;
            }
            *reinterpret_cast<bfrag*>(&sK[row * SLDA + seg * 8]) = v;
        }
        __syncthreads();
        if (!afLoaded) {
#pragma unroll
            for (int ks = 0; ks < 4; ks++)
                af[ks] = *reinterpret_cast<const bfrag*>(&sQ[(wave * 16 + l15) * SLDA + ks * 32 + quad * 8]);
            afLoaded = true;
        }
#pragma unroll
        for (int ks = 0; ks < 4; ks++) {
#pragma unroll
            for (int nt = 0; nt < 10; nt++) {
                bfrag bf = *reinterpret_cast<const bfrag*>(&sK[(nt * 16 + l15) * SLDA + ks * 32 + quad * 8]);
                acc[half * 10 + nt] = __builtin_amdgcn_mfma_f32_16x16x32_bf16(af[ks], bf, acc[half * 10 + nt], 0, 0, 0);
            }
        }
        __syncthreads();
    }

    const float scale = 0.08838834764831845f;
    const float inv_sqrt2 = 0.7071067811865475f;
#pragma unroll
    for (int nt = 0; nt < 20; nt++) {
        int col = nt * 16 + l15;
#pragma unroll
        for (int r = 0; r < 4; r++) {
            float v = acc[nt][r];
            float ge = 0.5f * v * (1.0f + erff(v * inv_sqrt2));
            float s = ge * scale;
            if (col >= C_) s = -FLT_MAX;
            acc[nt][r] = s;
        }
    }
    float mx[4], sm[4];
#pragma unroll
    for (int r = 0; r < 4; r++) {
        float m = -FLT_MAX;
#pragma unroll
        for (int nt = 0; nt < 20; nt++) m = fmaxf(m, acc[nt][r]);
        for (int o = 1; o < 16; o <<= 1) m = fmaxf(m, __shfl_xor(m, o));
        mx[r] = m;
    }
#pragma unroll
    for (int r = 0; r < 4; r++) {
        float s = 0.f;
#pragma unroll
        for (int nt = 0; nt < 20; nt++) {
            float e = __expf(acc[nt][r] - mx[r]);
            acc[nt][r] = e;
            s += e;
        }
        for (int o = 1; o < 16; o <<= 1) s += __shfl_xor(s, o);
        sm[r] = 1.0f / s;
    }
#pragma unroll
    for (int r = 0; r < 4; r++) {
        int row = strip * 64 + wave * 16 + quad * 4 + r;
        if (row >= C_) continue;
        float* ao = attnOut + ((size_t)bh * C_ + row) * C_;
#pragma unroll
        for (int nt = 0; nt < 20; nt++) {
            int col = nt * 16 + l15;
            if (col < C_) ao[col] = acc[nt][r] * sm[r];
        }
    }
}

// ---- MFMA attn @ V -> ctx (scrambled layout) --------------------------------
// Block = (bh, 32-row strip). P staged fp32->bf16 (k padded to 320 w/ zeros);
// V staged in frag-order LDS in two 160-row k-halves. 4 waves: 2 m-tiles x 2 n-halves.
#define PLDA 328   // 320 + 8 pad: row stride 656B = 164 dw, %32 = 4 banks
__global__ __launch_bounds__(256) void av_mfma_kernel(
        const float* __restrict__ attn, const bf16* __restrict__ vh_,
        bf16* __restrict__ ctx) {
    __shared__ __bf16 sP[32 * PLDA];        // 20992 B
    __shared__ __bf16 sV[5 * 8 * 64 * 8];   // 40960 B  [(kt,nt,lane) x 8]
    const __bf16* vh = reinterpret_cast<const __bf16*>(vh_);
    int strip = blockIdx.x;                 // 0..9 -> rows strip*32..+31
    int bh = blockIdx.y;
    int t = threadIdx.x;
    int lane = t & 63, wave = t >> 6;
    int quad = lane >> 4, l15 = lane & 15;
    int mt = wave & 1;                      // m-tile (16 rows)
    int nh = wave >> 1;                     // n-half (4 n-tiles of 16 cols)

    // stage P strip: fp32 attn -> bf16, cols padded to 320 with zeros
    for (int g = t; g < 32 * 80; g += 256) {
        int row = g / 80, col4 = g % 80;
        int src = strip * 32 + row; if (src > 311) src = 311;
        __bf16 pk[4];
        if (col4 < 78) {
            float4 a4 = *reinterpret_cast<const float4*>(attn + ((size_t)bh * C_ + src) * C_ + col4 * 4);
            pk[0] = (__bf16)a4.x; pk[1] = (__bf16)a4.y; pk[2] = (__bf16)a4.z; pk[3] = (__bf16)a4.w;
        } else {
            pk[0] = pk[1] = pk[2] = pk[3] = (__bf16)0.f;
        }
        *reinterpret_cast<uint2*>(&sP[row * PLDA + col4 * 4]) = *reinterpret_cast<const uint2*>(pk);
    }

    f32x4 acc[4];
#pragma unroll
    for (int i = 0; i < 4; i++) acc[i] = (f32x4)(0.f);

    for (int half = 0; half < 2; half++) {
        if (half) __syncthreads();   // all waves done reading sV of prev half
        // stage V rows [half*160, +160) into frag-order sV; zero-pad c >= 312
        for (int g = t; g < 160 * 16; g += 256) {
            int cl = g >> 4, dseg = g & 15;
            int src = half * 160 + cl;
            bfrag v;
            if (src < C_) {
                v = *reinterpret_cast<const bfrag*>(vh + ((size_t)bh * C_ + src) * D_ + dseg * 8);
            } else {
#pragma unroll
                for (int j = 0; j < 8; j++) v[j] = (__bf16)0.f;
            }
            int kt = cl >> 5, q2 = (cl >> 3) & 3, j = cl & 7;
#pragma unroll
            for (int j2 = 0; j2 < 8; j2++) {
                int d = dseg * 8 + j2;
                int nt = d >> 4, dl = d & 15;
                sV[(((kt * 8 + nt) * 64) + q2 * 16 + dl) * 8 + j] = v[j2];
            }
        }
        __syncthreads();
#pragma unroll
        for (int kt = 0; kt < 5; kt++) {
            bfrag a = *reinterpret_cast<const bfrag*>(
                &sP[(mt * 16 + l15) * PLDA + half * 160 + kt * 32 + quad * 8]);
#pragma unroll
            for (int ntl = 0; ntl < 4; ntl++) {
                int ntg = nh * 4 + ntl;
                bfrag b = *reinterpret_cast<const bfrag*>(&sV[(((kt * 8 + ntg) * 64) + lane) * 8]);
                acc[ntl] = __builtin_amdgcn_mfma_f32_16x16x32_bf16(a, b, acc[ntl], 0, 0, 0);
            }
        }
    }

    // epilogue: ctx[b, h*39 + c/8, (c%8)*128 + d], C-layout row = quad*4+r
    int b = bh >> 3, h = bh & 7;
#pragma unroll
    for (int ntl = 0; ntl < 4; ntl++) {
        int d = nh * 64 + ntl * 16 + l15;
#pragma unroll
        for (int r = 0; r < 4; r++) {
            int c = strip * 32 + mt * 16 + quad * 4 + r;
            if (c < C_) {
                size_t oi = ((size_t)b * C_ + h * 39 + (c >> 3)) * N_ + ((c & 7) << 7) + d;
                ctx[oi] = f2bf(acc[ntl][r]);
            }
        }
    }
}

// ---------------- L2 row norm (fp32 out) -------------------------------------
__global__ void norm_kernel(const float* __restrict__ out3, float* __restrict__ outp) {
    int r = blockIdx.x;
    const float* p = out3 + (size_t)r * N_;
    float sq = 0.f;
    for (int i = threadIdx.x; i < N_; i += 256) { float f = p[i]; sq += f * f; }
    __shared__ float rq[256];
    rq[threadIdx.x] = sq; __syncthreads();
    for (int o = 128; o > 0; o >>= 1) {
        if (threadIdx.x < o) rq[threadIdx.x] += rq[threadIdx.x + o];
        __syncthreads();
    }
    float inv = 1.0f / fmaxf(sqrtf(rq[0]), 1e-12f);
    float* po = outp + (size_t)r * N_;
    for (int i = threadIdx.x; i < N_; i += 256) po[i] = p[i] * inv;
}

// ---------------- host orchestration ----------------------------------------
extern "C" void kernel_launch(void* const* d_in, const int* in_sizes, int n_in,
                              void* d_out, int out_size, void* d_ws, size_t ws_size,
                              hipStream_t stream) {
    const float* x      = (const float*)d_in[0];
    const float* ln_q_g = (const float*)d_in[3];
    const float* ln_q_b = (const float*)d_in[4];
    const float* ln_k_g = (const float*)d_in[5];
    const float* ln_k_b = (const float*)d_in[6];
    const float* ln_v_g = (const float*)d_in[7];
    const float* ln_v_b = (const float*)d_in[8];
    const float* w_q    = (const float*)d_in[9];
    const float* w_k    = (const float*)d_in[10];
    const float* w_v    = (const float*)d_in[11];
    const float* w_proj = (const float*)d_in[12];
    const float* b_proj = (const float*)d_in[13];
    const float* dw0    = (const float*)d_in[14];
    const float* pw0    = (const float*)d_in[15];
    const float* gn_g   = (const float*)d_in[16];
    const float* gn_b   = (const float*)d_in[17];
    const float* dw1    = (const float*)d_in[18];
    const float* pw1    = (const float*)d_in[19];
    const float* dw2    = (const float*)d_in[20];
    const float* pw2    = (const float*)d_in[21];
    const float* bn0_g  = (const float*)d_in[22];
    const float* bn0_b  = (const float*)d_in[23];
    const float* bn0_m  = (const float*)d_in[24];
    const float* bn0_v  = (const float*)d_in[25];
    const float* bn1_g  = (const float*)d_in[26];
    const float* bn1_b  = (const float*)d_in[27];
    const float* bn1_m  = (const float*)d_in[28];
    const float* bn1_v  = (const float*)d_in[29];
    const float* bn2_g  = (const float*)d_in[30];
    const float* bn2_b  = (const float*)d_in[31];
    const float* bn2_m  = (const float*)d_in[32];
    const float* bn2_v  = (const float*)d_in[33];

    char* ws = (char*)d_ws;
    size_t off = 0;
    auto alloc = [&](size_t bytes) {
        void* p = ws + off;
        off = (off + bytes + 255) & ~(size_t)255;
        return p;
    };
    const size_t BF_BYTES = (size_t)BC_ * N_ * sizeof(bf16);
    bf16*  xn   = (bf16*)alloc(BF_BYTES);
    bf16*  qb   = (bf16*)alloc(BF_BYTES);
    bf16*  kb   = (bf16*)alloc(BF_BYTES);
    bf16*  vb   = (bf16*)alloc(BF_BYTES);
    float* tmp1 = (float*)alloc((size_t)B_ * SD_ * N_ * sizeof(float));
    float* tmp2 = (float*)alloc((size_t)B_ * SD_ * N_ * sizeof(float));
    float* gnst = (float*)alloc(512);
    bf16* qh  = xn;
    bf16* kh  = qb;
    bf16* vh  = kb;
    bf16* ctx = vb;
    float* out3 = (float*)xn;   // aliases xn+qb (dead after attn/av)

    float* out_main = (float*)d_out;
    float* attn_out = out_main + (size_t)BC_ * N_;

    dim3 gemm_grid(8, 78);

    hipLaunchKernelGGL(ln_kernel, dim3(BC_), dim3(256), 0, stream, x, xn);
    hipLaunchKernelGGL((mfma_gemm_kernel<false>), gemm_grid, dim3(256), 0, stream,
                       xn, ln_q_g, ln_q_b, w_q, (const float*)nullptr, (void*)qb);
    hipLaunchKernelGGL((mfma_gemm_kernel<false>), gemm_grid, dim3(256), 0, stream,
                       xn, ln_k_g, ln_k_b, w_k, (const float*)nullptr, (void*)kb);
    hipLaunchKernelGGL((mfma_gemm_kernel<false>), gemm_grid, dim3(256), 0, stream,
                       xn, ln_v_g, ln_v_b, w_v, (const float*)nullptr, (void*)vb);

    const bf16* tins[3] = {qb, kb, vb};
    bf16* thouts[3] = {qh, kh, vh};
    for (int i = 0; i < 3; i++) {
        const bf16* t = tins[i];
        bf16* th = thouts[i];
        dim3 g2496(B_ * SD_);
        hipLaunchKernelGGL(seg0_kernel, g2496, dim3(256), 0, stream,
                           t, th, bn0_g, bn0_b, bn0_m, bn0_v);
        hipLaunchKernelGGL((dw_kernel<3>), g2496, dim3(256), 0, stream, t, SD_, dw1, tmp1);
        hipLaunchKernelGGL((pw_kernel<0>), g2496, dim3(256), 0, stream,
                           tmp1, pw1, bn1_g, bn1_b, bn1_m, bn1_v, SD_, th, (float*)nullptr);
        hipLaunchKernelGGL((dw_kernel<5>), g2496, dim3(256), 0, stream, t, 2 * SD_, dw2, tmp1);
        hipLaunchKernelGGL((pw_kernel<0>), g2496, dim3(256), 0, stream,
                           tmp1, pw2, bn2_g, bn2_b, bn2_m, bn2_v, 2 * SD_, th, (float*)nullptr);
        hipLaunchKernelGGL((dw_kernel<3>), g2496, dim3(256), 0, stream, t, 3 * SD_, dw0, tmp1);
        hipLaunchKernelGGL((pw_kernel<1>), g2496, dim3(256), 0, stream,
                           tmp1, pw0, (const float*)nullptr, (const float*)nullptr,
                           (const float*)nullptr, (const float*)nullptr, 0, (bf16*)nullptr, tmp2);
        hipLaunchKernelGGL(gn_stats_kernel, dim3(B_ * 2), dim3(256), 0, stream, tmp2, gnst);
        hipLaunchKernelGGL(gn_apply_kernel, g2496, dim3(256), 0, stream, tmp2, gnst, gn_g, gn_b, th);
    }

    hipLaunchKernelGGL(attn_mfma_kernel, dim3(5, BH_), dim3(256), 0, stream, qh, kh, attn_out);
    hipLaunchKernelGGL(av_mfma_kernel, dim3(10, BH_), dim3(256), 0, stream, attn_out, vh, ctx);
    hipLaunchKernelGGL((mfma_gemm_kernel<true>), gemm_grid, dim3(256), 0, stream,
                       ctx, (const float*)nullptr, (const float*)nullptr, w_proj, b_proj,
                       (void*)out3);
    hipLaunchKernelGGL(norm_kernel, dim3(BC_), dim3(256), 0, stream, out3, out_main);
}